// Round 15
// baseline (774.938 us; speedup 1.0000x reference)
//
#include <hip/hip_runtime.h>
#include <hip/hip_cooperative_groups.h>

namespace cg = cooperative_groups;

// ---------------------------------------------------------------------------
// GIN (2 layers) + global mean pool, MI355X (gfx950).
// R15: collapse the 6-phase prep/CSR chain (detect, zero, conv+hist+packs,
// scan, scan_fix+perm, fill) into ONE cooperative kernel with grid.sync()
// phase gates — removes 5 kernel boundaries (~tail drain + launch each) and
// keeps ei L2-warm between hist and fill. Fused layer kernels unchanged
// (R14-proven: layer2 gather at measured random-row ceiling ~6.8 TB/s
// logical). 4 dispatches total.
// ---------------------------------------------------------------------------

typedef __bf16 bf16x8 __attribute__((ext_vector_type(8)));
typedef float f32x4 __attribute__((ext_vector_type(4)));

#define N_NODES 50000
#define N_EDGES 800000
#define N_GRAPHS 64
#define SCAN_BLOCKS 196
#define NREP 8
#define BUILD_BLOCKS 960

// P1 flat work ranges
#define U_CONV0 0
#define U_HIST0 800000
#define U_P0    1600000
#define U_P1    1632768
#define U_P2    1698304
#define U_P3    1763840
#define U_BIAS  1829376
#define U_TOTAL 1830400

#define OFF_FLAGS  0ull
#define OFF_WB     64ull
#define OFF_WP0    4096ull
#define OFF_WP1    (OFF_WP0 + 65536ull)
#define OFF_WP2    (OFF_WP1 + 131072ull)
#define OFF_WP3    (OFF_WP2 + 131072ull)
#define OFF_CNT    462848ull
#define OFF_ROWPTR 662864ull
#define OFF_CURSOR 862880ull
#define OFF_SSRC   1062912ull
#define OFF_A      2662912ull               // 12.8 MB
#define OFF_B      15462912ull              // 25.6 MB
#define OFF_POOL32 66662912ull              // 512 KB (8 replicas)
#define OFF_BSUM   67187200ull
#define OFF_PERM   67191296ull              // 200 KB

__device__ __forceinline__ float b2f(unsigned short u) {
  union { unsigned int i; float f; } v; v.i = ((unsigned int)u) << 16; return v.f;
}
__device__ __forceinline__ float b2f_lo(unsigned int u) {
  union { unsigned int i; float f; } v; v.i = u << 16; return v.f;
}
__device__ __forceinline__ float b2f_hi(unsigned int u) {
  union { unsigned int i; float f; } v; v.i = u & 0xffff0000u; return v.f;
}
__device__ __forceinline__ unsigned short f2b(float f) {
  union { unsigned int i; float f; } v; v.f = f;
  unsigned int r = v.i + 0x7fffu + ((v.i >> 16) & 1u);
  return (unsigned short)(r >> 16);
}
__device__ __forceinline__ unsigned int pk2(float hi, float lo) {
  return ((unsigned int)f2b(hi) << 16) | f2b(lo);
}
__device__ __forceinline__ void acc8(float* a, uint4 v) {
  a[0] += b2f_lo(v.x); a[1] += b2f_hi(v.x);
  a[2] += b2f_lo(v.y); a[3] += b2f_hi(v.y);
  a[4] += b2f_lo(v.z); a[5] += b2f_hi(v.z);
  a[6] += b2f_lo(v.w); a[7] += b2f_hi(v.w);
}
__device__ __forceinline__ void pack_w_elem(const void* W, unsigned short* Wp,
                                            int e, int isb) {
  int n = e & 255;
  int krow = e >> 8;
  int kb = krow >> 5, r = krow & 31;
  int q = r >> 3, j = r & 7;
  size_t out = ((((size_t)(kb << 8) + n) << 2) + q) * 8 + j;
  Wp[out] = isb ? ((const unsigned short*)W)[e] : f2b(((const float*)W)[e]);
}

// ---- one cooperative kernel: detect+zero | conv+hist+packs+bias | scan |
// scan_fix(+block-local degree-sorted perm) | fill
__global__ void __launch_bounds__(256) build_kernel(
    const void* __restrict__ x, const int* __restrict__ ei,
    const void* W0, const void* W1, const void* W2, const void* W3,
    const void* b0, const void* b1, const void* b2, const void* b3,
    char* __restrict__ ws) {
  cg::grid_group grid = cg::this_grid();
  int*            flags  = (int*)(ws + OFF_FLAGS);
  unsigned short* Wb     = (unsigned short*)(ws + OFF_WB);
  unsigned short* Wp0    = (unsigned short*)(ws + OFF_WP0);
  unsigned short* Wp1    = (unsigned short*)(ws + OFF_WP1);
  unsigned short* Wp2    = (unsigned short*)(ws + OFF_WP2);
  unsigned short* Wp3    = (unsigned short*)(ws + OFF_WP3);
  int*            counts = (int*)(ws + OFF_CNT);
  int*            rowptr = (int*)(ws + OFF_ROWPTR);
  int*            cursor = (int*)(ws + OFF_CURSOR);
  unsigned short* ssrc   = (unsigned short*)(ws + OFF_SSRC);
  unsigned short* A      = (unsigned short*)(ws + OFF_A);
  float*          pool32 = (float*)(ws + OFF_POOL32);
  int*            bsum   = (int*)(ws + OFF_BSUM);
  int*            perm   = (int*)(ws + OFF_PERM);

  __shared__ int sA[256], sB[256], sC[256];
  const int t = threadIdx.x;
  const int gtid = blockIdx.x * 256 + t;
  const int gs = gridDim.x * 256;

  // ---- P0: detect (block 0) + zero counts/pool32
  if (blockIdx.x == 0) {
    const unsigned int* xw = (const unsigned int*)x;
    const unsigned int* eiw = (const unsigned int*)ei;
    int fh = 0, iz = 0;
    for (int i = t; i < 1024; i += 256) {
      unsigned int e = (xw[i] >> 7) & 0xFFu;
      fh += (e >= 115u && e <= 130u) ? 1 : 0;
      iz += (eiw[2 * i + 1] == 0u) ? 1 : 0;
    }
    sA[t] = fh; sB[t] = iz;
    __syncthreads();
    for (int s = 128; s > 0; s >>= 1) {
      if (t < s) { sA[t] += sA[t + s]; sB[t] += sB[t + s]; }
      __syncthreads();
    }
    if (t == 0) { flags[0] = sA[0] > 512 ? 1 : 0; flags[1] = sB[0] > 512 ? 1 : 0; }
  }
  for (int i = gtid; i < NREP * N_GRAPHS * 256; i += gs) pool32[i] = 0.f;
  for (int i = gtid; i < N_NODES; i += gs) counts[i] = 0;
  grid.sync();

  // ---- P1: conv(f32 only) + hist + weight packs + bias
  const int isb = flags[0], i64 = flags[1];
  for (int u = gtid; u < U_TOTAL; u += gs) {
    if (u < U_HIST0) {
      if (!isb) {
        int i = u;
        const float4* f = (const float4*)x;
        float4 a = f[2 * i], c = f[2 * i + 1];
        ushort4 o0; o0.x = f2b(a.x); o0.y = f2b(a.y); o0.z = f2b(a.z); o0.w = f2b(a.w);
        ushort4 o1; o1.x = f2b(c.x); o1.y = f2b(c.y); o1.z = f2b(c.z); o1.w = f2b(c.w);
        ((ushort4*)A)[2 * i] = o0;
        ((ushort4*)A)[2 * i + 1] = o1;
      }
    } else if (u < U_P0) {
      int e = u - U_HIST0;
      int dst = i64 ? ei[2 * (N_EDGES + e)] : ei[N_EDGES + e];
      atomicAdd(&counts[dst], 1);
    } else if (u < U_P1) {
      pack_w_elem(W0, Wp0, u - U_P0, isb);
    } else if (u < U_P2) {
      pack_w_elem(W1, Wp1, u - U_P1, isb);
    } else if (u < U_P3) {
      pack_w_elem(W2, Wp2, u - U_P2, isb);
    } else if (u < U_BIAS) {
      pack_w_elem(W3, Wp3, u - U_P3, isb);
    } else {
      int i = u - U_BIAS;
      const void* p = (i < 256) ? b0 : (i < 512) ? b1 : (i < 768) ? b2 : b3;
      int n = i & 255;
      Wb[i] = isb ? ((const unsigned short*)p)[n] : f2b(((const float*)p)[n]);
    }
  }
  grid.sync();

  // ---- P2: per-window scan (windows 0..195)
  if (blockIdx.x < SCAN_BLOCKS) {
    int i = blockIdx.x * 256 + t;
    int v = (i < N_NODES) ? counts[i] : 0;
    sA[t] = v;
    __syncthreads();
    for (int off = 1; off < 256; off <<= 1) {
      int u = (t >= off) ? sA[t - off] : 0;
      __syncthreads();
      sA[t] += u;
      __syncthreads();
    }
    if (i < N_NODES) rowptr[i] = sA[t] - v;
    if (t == 255) bsum[blockIdx.x] = sA[255];
  }
  grid.sync();

  // ---- P3: apply chunk offsets + block-local degree sort -> perm
  if (blockIdx.x < SCAN_BLOCKS) {
    sA[t] = (t < SCAN_BLOCKS) ? bsum[t] : 0;   // sA = bsum scan
    sB[t] = 0; sC[t] = 0;                      // sB = lh, sC = lc2
    __syncthreads();
    for (int off = 1; off < 256; off <<= 1) {
      int u = (t >= off) ? sA[t - off] : 0;
      __syncthreads();
      sA[t] += u;
      __syncthreads();
    }
    int boffv = (blockIdx.x > 0) ? sA[blockIdx.x - 1] : 0;
    int i = blockIdx.x * 256 + t;
    int d = 0;
    int valid = (i < N_NODES);
    if (valid) {
      int v = rowptr[i] + boffv;
      rowptr[i] = v;
      cursor[i] = v;
      int c = counts[i];
      d = c > 255 ? 255 : c;
      atomicAdd(&sB[d], 1);
    }
    if (i == 0) rowptr[N_NODES] = N_EDGES;
    __syncthreads();
    int own = sB[t];
    for (int off = 1; off < 256; off <<= 1) {
      int u = (t >= off) ? sB[t - off] : 0;
      __syncthreads();
      sB[t] += u;
      __syncthreads();
    }
    int ex = sB[t] - own;
    __syncthreads();
    sB[t] = ex;
    __syncthreads();
    if (valid) {
      int r = sB[d] + atomicAdd(&sC[d], 1);
      perm[blockIdx.x * 256 + r] = i;
    }
  }
  grid.sync();

  // ---- P4: fill CSR adjacency (ei L2-warm from P1)
  for (int e = gtid; e < N_EDGES; e += gs) {
    int src = i64 ? ei[2 * e] : ei[e];
    int dst = i64 ? ei[2 * (N_EDGES + e)] : ei[N_EDGES + e];
    int pos = atomicAdd(&cursor[dst], 1);
    ssrc[pos] = (unsigned short)src;
  }
}

// ---- layer 1 fully fused (R14). Gather: 16 lanes/node, 4-edge unroll,
// indices pre-loaded + __shfl(w=16). MFMA1(K=128) -> Tlds -> MFMA2 -> B.
__global__ void __launch_bounds__(256) fused_layer1(
    const unsigned short* __restrict__ featCanon,
    const unsigned short* __restrict__ featRaw,
    const int* __restrict__ rowptr, const unsigned short* __restrict__ ssrc,
    const int* __restrict__ perm,
    const unsigned short* __restrict__ Wp0, const unsigned short* __restrict__ Wp1,
    const unsigned short* __restrict__ Wb,
    unsigned short* __restrict__ B, const int* __restrict__ flags) {
  __shared__ __align__(16) unsigned short Alds[16 * 136];
  __shared__ __align__(16) unsigned short Tlds[16 * 264];
  __shared__ int sp[16];
  const int row0 = blockIdx.x << 4;
  const int lane = threadIdx.x & 63;
  const int wave = threadIdx.x >> 6;
  const unsigned short* feat = flags[0] ? featRaw : featCanon;
  if (threadIdx.x < 16) sp[threadIdx.x] = perm[row0 + threadIdx.x];
  __syncthreads();

  {
    int sub = lane >> 4, l = lane & 15;
    int nl = (wave << 2) + sub;
    int node = sp[nl];
    int beg = rowptr[node], end = rowptr[node + 1];
    int deg = end - beg;
    int c = l << 3;
    float a[8];
#pragma unroll
    for (int j = 0; j < 8; ++j) a[j] = 0.f;
    acc8(a, *(const uint4*)(feat + (size_t)node * 128 + c));
    int pre0 = (l < deg) ? (int)ssrc[beg + l] : 0;
    int pre1 = (16 + l < deg) ? (int)ssrc[beg + 16 + l] : 0;
    int lim = deg < 32 ? deg : 32;
    int i = 0;
    for (; i + 3 < lim; i += 4) {
      uint4 v[4];
#pragma unroll
      for (int e = 0; e < 4; ++e) {
        int ee = i + e;
        int idx = __shfl(ee < 16 ? pre0 : pre1, ee & 15, 16);
        v[e] = *(const uint4*)(feat + (size_t)idx * 128 + c);
      }
#pragma unroll
      for (int e = 0; e < 4; ++e) acc8(a, v[e]);
    }
    for (; i < lim; ++i) {
      int idx = __shfl(i < 16 ? pre0 : pre1, i & 15, 16);
      acc8(a, *(const uint4*)(feat + (size_t)idx * 128 + c));
    }
    for (; i < deg; ++i)
      acc8(a, *(const uint4*)(feat + (size_t)ssrc[beg + i] * 128 + c));
    uint4 o;
    o.x = pk2(a[1], a[0]); o.y = pk2(a[3], a[2]);
    o.z = pk2(a[5], a[4]); o.w = pk2(a[7], a[6]);
    *(uint4*)(&Alds[nl * 136 + c]) = o;
  }
  __syncthreads();

  const int m = lane & 15, q = lane >> 4;
  {  // MFMA1: K=128
    f32x4 acc[4];
#pragma unroll
    for (int t = 0; t < 4; ++t) acc[t] = (f32x4){0.f, 0.f, 0.f, 0.f};
    const unsigned short* arow = &Alds[m * 136 + (q << 3)];
    const int nb = (wave << 6) + m;
#pragma unroll
    for (int kb = 0; kb < 4; ++kb) {
      bf16x8 af = *(const bf16x8*)(arow + (kb << 5));
      const unsigned short* wp = Wp0 + (((size_t)(kb << 8) + nb) * 4 + q) * 8;
      acc[0] = __builtin_amdgcn_mfma_f32_16x16x32_bf16(af, *(const bf16x8*)(wp), acc[0], 0, 0, 0);
      acc[1] = __builtin_amdgcn_mfma_f32_16x16x32_bf16(af, *(const bf16x8*)(wp + 512), acc[1], 0, 0, 0);
      acc[2] = __builtin_amdgcn_mfma_f32_16x16x32_bf16(af, *(const bf16x8*)(wp + 1024), acc[2], 0, 0, 0);
      acc[3] = __builtin_amdgcn_mfma_f32_16x16x32_bf16(af, *(const bf16x8*)(wp + 1536), acc[3], 0, 0, 0);
    }
#pragma unroll
    for (int t = 0; t < 4; ++t) {
      int n = (wave << 6) + (t << 4) + m;
      float bv = b2f(Wb[n]);
#pragma unroll
      for (int i = 0; i < 4; ++i)
        Tlds[((q << 2) + i) * 264 + n] = f2b(fmaxf(acc[t][i] + bv, 0.f));
    }
  }
  __syncthreads();

  {  // MFMA2: K=256
    f32x4 acc[4];
#pragma unroll
    for (int t = 0; t < 4; ++t) acc[t] = (f32x4){0.f, 0.f, 0.f, 0.f};
    const unsigned short* arow = &Tlds[m * 264 + (q << 3)];
    const int nb = (wave << 6) + m;
#pragma unroll
    for (int kb = 0; kb < 8; ++kb) {
      bf16x8 af = *(const bf16x8*)(arow + (kb << 5));
      const unsigned short* wp = Wp1 + (((size_t)(kb << 8) + nb) * 4 + q) * 8;
      acc[0] = __builtin_amdgcn_mfma_f32_16x16x32_bf16(af, *(const bf16x8*)(wp), acc[0], 0, 0, 0);
      acc[1] = __builtin_amdgcn_mfma_f32_16x16x32_bf16(af, *(const bf16x8*)(wp + 512), acc[1], 0, 0, 0);
      acc[2] = __builtin_amdgcn_mfma_f32_16x16x32_bf16(af, *(const bf16x8*)(wp + 1024), acc[2], 0, 0, 0);
      acc[3] = __builtin_amdgcn_mfma_f32_16x16x32_bf16(af, *(const bf16x8*)(wp + 1536), acc[3], 0, 0, 0);
    }
#pragma unroll
    for (int t = 0; t < 4; ++t) {
      int n = (wave << 6) + (t << 4) + m;
      float bv = b2f(Wb[256 + n]);
#pragma unroll
      for (int i = 0; i < 4; ++i) {
        int r = sp[(q << 2) + i];
        B[(size_t)r * 256 + n] = f2b(fmaxf(acc[t][i] + bv, 0.f));
      }
    }
  }
}

// ---- layer 2 fully fused (R14). Gather: 32 lanes/node, 4-edge unroll,
// prefetched indices + __shfl(w=32). 512 thr / 8 waves.
__global__ void __launch_bounds__(512) fused_layer2(
    const unsigned short* __restrict__ B,
    const int* __restrict__ rowptr, const unsigned short* __restrict__ ssrc,
    const int* __restrict__ perm,
    const unsigned short* __restrict__ Wp2, const unsigned short* __restrict__ Wp3,
    const unsigned short* __restrict__ Wb,
    float* __restrict__ pool32, const int* __restrict__ batch,
    const int* __restrict__ flags) {
  __shared__ __align__(16) unsigned short Alds[16 * 264];
  __shared__ __align__(16) unsigned short Tlds[16 * 264];
  __shared__ int sp[16], sg[16], uni;
  const int row0 = blockIdx.x << 4;
  const int lane = threadIdx.x & 63;
  const int wave = threadIdx.x >> 6;   // 0..7
  if (threadIdx.x < 16) {
    int p = perm[row0 + threadIdx.x];
    sp[threadIdx.x] = p;
    sg[threadIdx.x] = flags[1] ? batch[2 * p] : batch[p];
  }
  __syncthreads();
  if (threadIdx.x == 0) {
    int u = 1;
#pragma unroll
    for (int i = 1; i < 16; ++i) u &= (sg[i] == sg[0]);
    uni = u;
  }

  {
    int sub = lane >> 5, l = lane & 31;
    int nl = (wave << 1) + sub;
    int node = sp[nl];
    int beg = rowptr[node], end = rowptr[node + 1];
    int deg = end - beg;
    int c = l << 3;
    float a[8];
#pragma unroll
    for (int j = 0; j < 8; ++j) a[j] = 0.f;
    acc8(a, *(const uint4*)(B + (size_t)node * 256 + c));
    int pre0 = (l < deg) ? (int)ssrc[beg + l] : 0;
    int pre1 = (32 + l < deg) ? (int)ssrc[beg + 32 + l] : 0;
    int lim = deg < 64 ? deg : 64;
    int i = 0;
    for (; i + 3 < lim; i += 4) {
      uint4 v[4];
#pragma unroll
      for (int e = 0; e < 4; ++e) {
        int ee = i + e;
        int idx = __shfl(ee < 32 ? pre0 : pre1, ee & 31, 32);
        v[e] = *(const uint4*)(B + (size_t)idx * 256 + c);
      }
#pragma unroll
      for (int e = 0; e < 4; ++e) acc8(a, v[e]);
    }
    for (; i < lim; ++i) {
      int idx = __shfl(i < 32 ? pre0 : pre1, i & 31, 32);
      acc8(a, *(const uint4*)(B + (size_t)idx * 256 + c));
    }
    for (; i < deg; ++i)
      acc8(a, *(const uint4*)(B + (size_t)ssrc[beg + i] * 256 + c));
    uint4 o;
    o.x = pk2(a[1], a[0]); o.y = pk2(a[3], a[2]);
    o.z = pk2(a[5], a[4]); o.w = pk2(a[7], a[6]);
    *(uint4*)(&Alds[nl * 264 + c]) = o;
  }
  __syncthreads();

  const int m = lane & 15, q = lane >> 4;
  {  // MFMA1: K=256, each wave covers 32 cols
    f32x4 acc[2];
    acc[0] = (f32x4){0.f, 0.f, 0.f, 0.f};
    acc[1] = (f32x4){0.f, 0.f, 0.f, 0.f};
    const unsigned short* arow = &Alds[m * 264 + (q << 3)];
    const int nb = (wave << 5) + m;
#pragma unroll
    for (int kb = 0; kb < 8; ++kb) {
      bf16x8 af = *(const bf16x8*)(arow + (kb << 5));
      const unsigned short* wp = Wp2 + (((size_t)(kb << 8) + nb) * 4 + q) * 8;
      acc[0] = __builtin_amdgcn_mfma_f32_16x16x32_bf16(af, *(const bf16x8*)(wp), acc[0], 0, 0, 0);
      acc[1] = __builtin_amdgcn_mfma_f32_16x16x32_bf16(af, *(const bf16x8*)(wp + 512), acc[1], 0, 0, 0);
    }
#pragma unroll
    for (int t = 0; t < 2; ++t) {
      int n = (wave << 5) + (t << 4) + m;
      float bv = b2f(Wb[512 + n]);
#pragma unroll
      for (int i = 0; i < 4; ++i)
        Tlds[((q << 2) + i) * 264 + n] = f2b(fmaxf(acc[t][i] + bv, 0.f));
    }
  }
  __syncthreads();

  {  // MFMA2: K=256 -> pool epilogue
    f32x4 acc[2];
    acc[0] = (f32x4){0.f, 0.f, 0.f, 0.f};
    acc[1] = (f32x4){0.f, 0.f, 0.f, 0.f};
    const unsigned short* arow = &Tlds[m * 264 + (q << 3)];
    const int nb = (wave << 5) + m;
#pragma unroll
    for (int kb = 0; kb < 8; ++kb) {
      bf16x8 af = *(const bf16x8*)(arow + (kb << 5));
      const unsigned short* wp = Wp3 + (((size_t)(kb << 8) + nb) * 4 + q) * 8;
      acc[0] = __builtin_amdgcn_mfma_f32_16x16x32_bf16(af, *(const bf16x8*)(wp), acc[0], 0, 0, 0);
      acc[1] = __builtin_amdgcn_mfma_f32_16x16x32_bf16(af, *(const bf16x8*)(wp + 512), acc[1], 0, 0, 0);
    }
    float* pr = pool32 + ((blockIdx.x & (NREP - 1)) << 14);
    int u = uni;
#pragma unroll
    for (int t = 0; t < 2; ++t) {
      int n = (wave << 5) + (t << 4) + m;
      float bv = b2f(Wb[768 + n]);
      float v0 = fmaxf(acc[t][0] + bv, 0.f);
      float v1 = fmaxf(acc[t][1] + bv, 0.f);
      float v2 = fmaxf(acc[t][2] + bv, 0.f);
      float v3 = fmaxf(acc[t][3] + bv, 0.f);
      if (u) {
        float ps = v0 + v1 + v2 + v3;
        ps += __shfl_xor(ps, 16);
        ps += __shfl_xor(ps, 32);
        if (q == 0) unsafeAtomicAdd(&pr[sg[0] * 256 + n], ps);
      } else {
        float vv[4] = {v0, v1, v2, v3};
        int gp = sg[q << 2];
        float a = 0.f;
#pragma unroll
        for (int i = 0; i < 4; ++i) {
          int g = sg[(q << 2) + i];
          if (g != gp) { unsafeAtomicAdd(&pr[gp * 256 + n], a); a = 0.f; gp = g; }
          a += vv[i];
        }
        unsafeAtomicAdd(&pr[gp * 256 + n], a);
      }
    }
  }
}

// ---- finalize: sum replicas, divide, dtype-aware store
__device__ __forceinline__ int lower_bound(const int* a, int n, int v, int is64) {
  int lo = 0, hi = n;
  while (lo < hi) {
    int mid = (lo + hi) >> 1;
    int bv = is64 ? a[2 * mid] : a[mid];
    if (bv < v) lo = mid + 1; else hi = mid;
  }
  return lo;
}

__global__ void pool_final(const float* __restrict__ pool32,
                           const int* __restrict__ batch,
                           void* __restrict__ out,
                           const int* __restrict__ flags) {
  __shared__ int sh[2];
  int g = blockIdx.x;
  int is64 = flags[1];
  if (threadIdx.x == 0) sh[0] = lower_bound(batch, N_NODES, g, is64);
  if (threadIdx.x == 1) sh[1] = lower_bound(batch, N_NODES, g + 1, is64);
  __syncthreads();
  int c = threadIdx.x;
  float s = 0.f;
#pragma unroll
  for (int r = 0; r < NREP; ++r) s += pool32[(r << 14) + g * 256 + c];
  float res = s / fmaxf((float)(sh[1] - sh[0]), 1.0f);
  if (flags[0]) ((unsigned short*)out)[(size_t)g * 256 + c] = f2b(res);
  else          ((float*)out)[(size_t)g * 256 + c] = res;
}

extern "C" void kernel_launch(void* const* d_in, const int* in_sizes, int n_in,
                              void* d_out, int out_size, void* d_ws, size_t ws_size,
                              hipStream_t stream) {
  const void* x    = d_in[0];
  const int*  ei   = (const int*)d_in[1];
  const int*  batch= (const int*)d_in[2];
  const void* W0 = d_in[3];
  const void* bb0 = d_in[4];
  const void* W1 = d_in[5];
  const void* bb1 = d_in[6];
  const void* W2 = d_in[7];
  const void* bb2 = d_in[8];
  const void* W3 = d_in[9];
  const void* bb3 = d_in[10];

  char* ws = (char*)d_ws;
  int*            flags = (int*)(ws + OFF_FLAGS);
  unsigned short* Wb    = (unsigned short*)(ws + OFF_WB);
  unsigned short* Wp0   = (unsigned short*)(ws + OFF_WP0);
  unsigned short* Wp1   = (unsigned short*)(ws + OFF_WP1);
  unsigned short* Wp2   = (unsigned short*)(ws + OFF_WP2);
  unsigned short* Wp3   = (unsigned short*)(ws + OFF_WP3);
  int*            rowp  = (int*)(ws + OFF_ROWPTR);
  unsigned short* ssrc  = (unsigned short*)(ws + OFF_SSRC);
  unsigned short* A     = (unsigned short*)(ws + OFF_A);
  unsigned short* B     = (unsigned short*)(ws + OFF_B);
  float*          pool32= (float*)(ws + OFF_POOL32);
  int*            perm  = (int*)(ws + OFF_PERM);

  void* kargs[] = { (void*)&x, (void*)&ei,
                    (void*)&W0, (void*)&W1, (void*)&W2, (void*)&W3,
                    (void*)&bb0, (void*)&bb1, (void*)&bb2, (void*)&bb3,
                    (void*)&ws };
  hipLaunchCooperativeKernel((const void*)build_kernel,
                             dim3(BUILD_BLOCKS), dim3(256), kargs, 0, stream);

  fused_layer1<<<3125, 256, 0, stream>>>(A, (const unsigned short*)x, rowp, ssrc,
                                         perm, Wp0, Wp1, Wb, B, flags);
  fused_layer2<<<3125, 512, 0, stream>>>(B, rowp, ssrc, perm, Wp2, Wp3, Wb,
                                         pool32, batch, flags);

  pool_final<<<N_GRAPHS, 256, 0, stream>>>(pool32, batch, d_out, flags);
}

// Round 16
// 333.318 us; speedup vs baseline: 2.3249x; 2.3249x over previous
//
#include <hip/hip_runtime.h>

// ---------------------------------------------------------------------------
// GIN (2 layers) + global mean pool, MI355X (gfx950).
// R16: revert to R14 (session best 339us). R15's cooperative build_kernel
// regressed 2.3x — grid.sync() at 960 blocks costs ~100us+ each on MI355X,
// far more than the ~5us kernel boundaries it replaced. Micro-trim: pool32
// zeroing moved from detect_zero into scan_blocks (grid-stride).
// 8 dispatches.
// ---------------------------------------------------------------------------

typedef __bf16 bf16x8 __attribute__((ext_vector_type(8)));
typedef float f32x4 __attribute__((ext_vector_type(4)));

#define N_NODES 50000
#define N_EDGES 800000
#define N_GRAPHS 64
#define SCAN_BLOCKS 196
#define NREP 8

// prep kernel block ranges
#define PB_HIST0 3125
#define PB_P0    6250
#define PB_P1    6378
#define PB_P2    6634
#define PB_P3    6890
#define PB_BIAS  7146
#define PB_TOTAL 7150

#define OFF_FLAGS  0ull
#define OFF_WB     64ull
#define OFF_WP0    4096ull
#define OFF_WP1    (OFF_WP0 + 65536ull)
#define OFF_WP2    (OFF_WP1 + 131072ull)
#define OFF_WP3    (OFF_WP2 + 131072ull)
#define OFF_CNT    462848ull
#define OFF_ROWPTR 662864ull
#define OFF_CURSOR 862880ull
#define OFF_SSRC   1062912ull
#define OFF_A      2662912ull               // 12.8 MB
#define OFF_B      15462912ull              // 25.6 MB
#define OFF_POOL32 66662912ull              // 512 KB (8 replicas)
#define OFF_BSUM   67187200ull
#define OFF_PERM   67191296ull              // 200 KB

__device__ __forceinline__ float b2f(unsigned short u) {
  union { unsigned int i; float f; } v; v.i = ((unsigned int)u) << 16; return v.f;
}
__device__ __forceinline__ float b2f_lo(unsigned int u) {
  union { unsigned int i; float f; } v; v.i = u << 16; return v.f;
}
__device__ __forceinline__ float b2f_hi(unsigned int u) {
  union { unsigned int i; float f; } v; v.i = u & 0xffff0000u; return v.f;
}
__device__ __forceinline__ unsigned short f2b(float f) {
  union { unsigned int i; float f; } v; v.f = f;
  unsigned int r = v.i + 0x7fffu + ((v.i >> 16) & 1u);
  return (unsigned short)(r >> 16);
}
__device__ __forceinline__ unsigned int pk2(float hi, float lo) {
  return ((unsigned int)f2b(hi) << 16) | f2b(lo);
}
__device__ __forceinline__ void acc8(float* a, uint4 v) {
  a[0] += b2f_lo(v.x); a[1] += b2f_hi(v.x);
  a[2] += b2f_lo(v.y); a[3] += b2f_hi(v.y);
  a[4] += b2f_lo(v.z); a[5] += b2f_hi(v.z);
  a[6] += b2f_lo(v.w); a[7] += b2f_hi(v.w);
}

// ---- block 0: dtype detect; blocks 1..196: zero counts
__global__ void detect_zero(const unsigned int* __restrict__ xw,
                            const unsigned int* __restrict__ eiw,
                            int* __restrict__ flags,
                            int* __restrict__ counts) {
  if (blockIdx.x == 0) {
    __shared__ int s_f[256], s_i[256];
    int t = threadIdx.x;
    int fh = 0, iz = 0;
    for (int i = t; i < 1024; i += 256) {
      unsigned int e = (xw[i] >> 7) & 0xFFu;
      fh += (e >= 115u && e <= 130u) ? 1 : 0;
      iz += (eiw[2 * i + 1] == 0u) ? 1 : 0;
    }
    s_f[t] = fh; s_i[t] = iz;
    __syncthreads();
    for (int s = 128; s > 0; s >>= 1) {
      if (t < s) { s_f[t] += s_f[t + s]; s_i[t] += s_i[t + s]; }
      __syncthreads();
    }
    if (t == 0) { flags[0] = s_f[0] > 512 ? 1 : 0; flags[1] = s_i[0] > 512 ? 1 : 0; }
  } else {
    int i = (blockIdx.x - 1) * 256 + threadIdx.x;
    if (i < N_NODES) counts[i] = 0;
  }
}

// ---- prep: conv(f32 only) + edge-dst hist + 4 weight packs + bias
__device__ __forceinline__ void pack_w_elem(const void* W, unsigned short* Wp,
                                            int e, int isb) {
  int n = e & 255;
  int krow = e >> 8;
  int kb = krow >> 5, r = krow & 31;
  int q = r >> 3, j = r & 7;
  size_t out = ((((size_t)(kb << 8) + n) << 2) + q) * 8 + j;
  Wp[out] = isb ? ((const unsigned short*)W)[e] : f2b(((const float*)W)[e]);
}

__global__ void prep_kernel(const void* __restrict__ x, const int* __restrict__ ei,
                            const void* W0, const void* W1, const void* W2, const void* W3,
                            const void* b0, const void* b1, const void* b2, const void* b3,
                            unsigned short* __restrict__ A,
                            int* __restrict__ counts,
                            unsigned short* __restrict__ Wp0, unsigned short* __restrict__ Wp1,
                            unsigned short* __restrict__ Wp2, unsigned short* __restrict__ Wp3,
                            unsigned short* __restrict__ Wb,
                            const int* __restrict__ flags) {
  int b = blockIdx.x, t = threadIdx.x;
  int isb = flags[0];
  if (b < PB_HIST0) {
    if (!isb) {
      int i = b * 256 + t;
      const float4* f = (const float4*)x;
      float4 a = f[2 * i], c = f[2 * i + 1];
      ushort4 o0; o0.x = f2b(a.x); o0.y = f2b(a.y); o0.z = f2b(a.z); o0.w = f2b(a.w);
      ushort4 o1; o1.x = f2b(c.x); o1.y = f2b(c.y); o1.z = f2b(c.z); o1.w = f2b(c.w);
      ((ushort4*)A)[2 * i] = o0;
      ((ushort4*)A)[2 * i + 1] = o1;
    }
  } else if (b < PB_P0) {
    int e = (b - PB_HIST0) * 256 + t;
    int dst = flags[1] ? ei[2 * (N_EDGES + e)] : ei[N_EDGES + e];
    atomicAdd(&counts[dst], 1);
  } else if (b < PB_P1) {
    pack_w_elem(W0, Wp0, (b - PB_P0) * 256 + t, isb);
  } else if (b < PB_P2) {
    pack_w_elem(W1, Wp1, (b - PB_P1) * 256 + t, isb);
  } else if (b < PB_P3) {
    pack_w_elem(W2, Wp2, (b - PB_P2) * 256 + t, isb);
  } else if (b < PB_BIAS) {
    pack_w_elem(W3, Wp3, (b - PB_P3) * 256 + t, isb);
  } else {
    int i = (b - PB_BIAS) * 256 + t;
    const void* p = (i < 256) ? b0 : (i < 512) ? b1 : (i < 768) ? b2 : b3;
    int n = i & 255;
    Wb[i] = isb ? ((const unsigned short*)p)[n] : f2b(((const float*)p)[n]);
  }
}

// ---- scan stage 1 (+ pool32 zeroing, grid-stride)
__global__ void scan_blocks(const int* __restrict__ counts,
                            int* __restrict__ rowptr, int* __restrict__ bsum,
                            float* __restrict__ pool32) {
  __shared__ int sd[256];
  int t = threadIdx.x;
  int i = blockIdx.x * 256 + t;
  for (int j = i; j < NREP * N_GRAPHS * 256; j += SCAN_BLOCKS * 256) pool32[j] = 0.f;
  int v = (i < N_NODES) ? counts[i] : 0;
  sd[t] = v;
  __syncthreads();
  for (int off = 1; off < 256; off <<= 1) {
    int u = (t >= off) ? sd[t - off] : 0;
    __syncthreads();
    sd[t] += u;
    __syncthreads();
  }
  if (i < N_NODES) rowptr[i] = sd[t] - v;
  if (t == 255) bsum[blockIdx.x] = sd[255];
}

// ---- scan stage 2: chunk offsets + block-local degree sort -> perm
__global__ void scan_fix(int* __restrict__ rowptr, int* __restrict__ cursor,
                         const int* __restrict__ bsum, const int* __restrict__ counts,
                         int* __restrict__ perm) {
  __shared__ int sb[256], lh[256], lc2[256];
  int t = threadIdx.x;
  sb[t] = (t < SCAN_BLOCKS) ? bsum[t] : 0;
  lh[t] = 0; lc2[t] = 0;
  __syncthreads();
  for (int off = 1; off < 256; off <<= 1) {
    int u = (t >= off) ? sb[t - off] : 0;
    __syncthreads();
    sb[t] += u;
    __syncthreads();
  }
  int boffv = (blockIdx.x > 0) ? sb[blockIdx.x - 1] : 0;
  int i = blockIdx.x * 256 + t;
  int d = 0;
  int valid = (i < N_NODES);
  if (valid) {
    int v = rowptr[i] + boffv;
    rowptr[i] = v;
    cursor[i] = v;
    int c = counts[i];
    d = c > 255 ? 255 : c;
    atomicAdd(&lh[d], 1);
  }
  if (i == 0) rowptr[N_NODES] = N_EDGES;
  __syncthreads();
  int own = lh[t];
  for (int off = 1; off < 256; off <<= 1) {
    int u = (t >= off) ? lh[t - off] : 0;
    __syncthreads();
    lh[t] += u;
    __syncthreads();
  }
  int ex = lh[t] - own;
  __syncthreads();
  lh[t] = ex;
  __syncthreads();
  if (valid) {
    int r = lh[d] + atomicAdd(&lc2[d], 1);
    perm[blockIdx.x * 256 + r] = i;
  }
}

__global__ void fill_kernel(const int* __restrict__ ei, int* __restrict__ cursor,
                            unsigned short* __restrict__ ssrc,
                            const int* __restrict__ flags) {
  int e = blockIdx.x * blockDim.x + threadIdx.x;
  if (e >= N_EDGES) return;
  int is64 = flags[1];
  int src = is64 ? ei[2 * e] : ei[e];
  int dst = is64 ? ei[2 * (N_EDGES + e)] : ei[N_EDGES + e];
  int pos = atomicAdd(&cursor[dst], 1);
  ssrc[pos] = (unsigned short)src;
}

// ---- layer 1 fully fused (R14). Gather: 16 lanes/node, 4-edge unroll,
// indices pre-loaded + __shfl(w=16). MFMA1(K=128) -> Tlds -> MFMA2 -> B.
__global__ void __launch_bounds__(256) fused_layer1(
    const unsigned short* __restrict__ featCanon,
    const unsigned short* __restrict__ featRaw,
    const int* __restrict__ rowptr, const unsigned short* __restrict__ ssrc,
    const int* __restrict__ perm,
    const unsigned short* __restrict__ Wp0, const unsigned short* __restrict__ Wp1,
    const unsigned short* __restrict__ Wb,
    unsigned short* __restrict__ B, const int* __restrict__ flags) {
  __shared__ __align__(16) unsigned short Alds[16 * 136];
  __shared__ __align__(16) unsigned short Tlds[16 * 264];
  __shared__ int sp[16];
  const int row0 = blockIdx.x << 4;
  const int lane = threadIdx.x & 63;
  const int wave = threadIdx.x >> 6;
  const unsigned short* feat = flags[0] ? featRaw : featCanon;
  if (threadIdx.x < 16) sp[threadIdx.x] = perm[row0 + threadIdx.x];
  __syncthreads();

  {
    int sub = lane >> 4, l = lane & 15;
    int nl = (wave << 2) + sub;
    int node = sp[nl];
    int beg = rowptr[node], end = rowptr[node + 1];
    int deg = end - beg;
    int c = l << 3;
    float a[8];
#pragma unroll
    for (int j = 0; j < 8; ++j) a[j] = 0.f;
    acc8(a, *(const uint4*)(feat + (size_t)node * 128 + c));
    int pre0 = (l < deg) ? (int)ssrc[beg + l] : 0;
    int pre1 = (16 + l < deg) ? (int)ssrc[beg + 16 + l] : 0;
    int lim = deg < 32 ? deg : 32;
    int i = 0;
    for (; i + 3 < lim; i += 4) {
      uint4 v[4];
#pragma unroll
      for (int e = 0; e < 4; ++e) {
        int ee = i + e;
        int idx = __shfl(ee < 16 ? pre0 : pre1, ee & 15, 16);
        v[e] = *(const uint4*)(feat + (size_t)idx * 128 + c);
      }
#pragma unroll
      for (int e = 0; e < 4; ++e) acc8(a, v[e]);
    }
    for (; i < lim; ++i) {
      int idx = __shfl(i < 16 ? pre0 : pre1, i & 15, 16);
      acc8(a, *(const uint4*)(feat + (size_t)idx * 128 + c));
    }
    for (; i < deg; ++i)
      acc8(a, *(const uint4*)(feat + (size_t)ssrc[beg + i] * 128 + c));
    uint4 o;
    o.x = pk2(a[1], a[0]); o.y = pk2(a[3], a[2]);
    o.z = pk2(a[5], a[4]); o.w = pk2(a[7], a[6]);
    *(uint4*)(&Alds[nl * 136 + c]) = o;
  }
  __syncthreads();

  const int m = lane & 15, q = lane >> 4;
  {  // MFMA1: K=128
    f32x4 acc[4];
#pragma unroll
    for (int t = 0; t < 4; ++t) acc[t] = (f32x4){0.f, 0.f, 0.f, 0.f};
    const unsigned short* arow = &Alds[m * 136 + (q << 3)];
    const int nb = (wave << 6) + m;
#pragma unroll
    for (int kb = 0; kb < 4; ++kb) {
      bf16x8 af = *(const bf16x8*)(arow + (kb << 5));
      const unsigned short* wp = Wp0 + (((size_t)(kb << 8) + nb) * 4 + q) * 8;
      acc[0] = __builtin_amdgcn_mfma_f32_16x16x32_bf16(af, *(const bf16x8*)(wp), acc[0], 0, 0, 0);
      acc[1] = __builtin_amdgcn_mfma_f32_16x16x32_bf16(af, *(const bf16x8*)(wp + 512), acc[1], 0, 0, 0);
      acc[2] = __builtin_amdgcn_mfma_f32_16x16x32_bf16(af, *(const bf16x8*)(wp + 1024), acc[2], 0, 0, 0);
      acc[3] = __builtin_amdgcn_mfma_f32_16x16x32_bf16(af, *(const bf16x8*)(wp + 1536), acc[3], 0, 0, 0);
    }
#pragma unroll
    for (int t = 0; t < 4; ++t) {
      int n = (wave << 6) + (t << 4) + m;
      float bv = b2f(Wb[n]);
#pragma unroll
      for (int i = 0; i < 4; ++i)
        Tlds[((q << 2) + i) * 264 + n] = f2b(fmaxf(acc[t][i] + bv, 0.f));
    }
  }
  __syncthreads();

  {  // MFMA2: K=256
    f32x4 acc[4];
#pragma unroll
    for (int t = 0; t < 4; ++t) acc[t] = (f32x4){0.f, 0.f, 0.f, 0.f};
    const unsigned short* arow = &Tlds[m * 264 + (q << 3)];
    const int nb = (wave << 6) + m;
#pragma unroll
    for (int kb = 0; kb < 8; ++kb) {
      bf16x8 af = *(const bf16x8*)(arow + (kb << 5));
      const unsigned short* wp = Wp1 + (((size_t)(kb << 8) + nb) * 4 + q) * 8;
      acc[0] = __builtin_amdgcn_mfma_f32_16x16x32_bf16(af, *(const bf16x8*)(wp), acc[0], 0, 0, 0);
      acc[1] = __builtin_amdgcn_mfma_f32_16x16x32_bf16(af, *(const bf16x8*)(wp + 512), acc[1], 0, 0, 0);
      acc[2] = __builtin_amdgcn_mfma_f32_16x16x32_bf16(af, *(const bf16x8*)(wp + 1024), acc[2], 0, 0, 0);
      acc[3] = __builtin_amdgcn_mfma_f32_16x16x32_bf16(af, *(const bf16x8*)(wp + 1536), acc[3], 0, 0, 0);
    }
#pragma unroll
    for (int t = 0; t < 4; ++t) {
      int n = (wave << 6) + (t << 4) + m;
      float bv = b2f(Wb[256 + n]);
#pragma unroll
      for (int i = 0; i < 4; ++i) {
        int r = sp[(q << 2) + i];
        B[(size_t)r * 256 + n] = f2b(fmaxf(acc[t][i] + bv, 0.f));
      }
    }
  }
}

// ---- layer 2 fully fused (R14). Gather: 32 lanes/node, 4-edge unroll,
// prefetched indices + __shfl(w=32). 512 thr / 8 waves.
__global__ void __launch_bounds__(512) fused_layer2(
    const unsigned short* __restrict__ B,
    const int* __restrict__ rowptr, const unsigned short* __restrict__ ssrc,
    const int* __restrict__ perm,
    const unsigned short* __restrict__ Wp2, const unsigned short* __restrict__ Wp3,
    const unsigned short* __restrict__ Wb,
    float* __restrict__ pool32, const int* __restrict__ batch,
    const int* __restrict__ flags) {
  __shared__ __align__(16) unsigned short Alds[16 * 264];
  __shared__ __align__(16) unsigned short Tlds[16 * 264];
  __shared__ int sp[16], sg[16], uni;
  const int row0 = blockIdx.x << 4;
  const int lane = threadIdx.x & 63;
  const int wave = threadIdx.x >> 6;   // 0..7
  if (threadIdx.x < 16) {
    int p = perm[row0 + threadIdx.x];
    sp[threadIdx.x] = p;
    sg[threadIdx.x] = flags[1] ? batch[2 * p] : batch[p];
  }
  __syncthreads();
  if (threadIdx.x == 0) {
    int u = 1;
#pragma unroll
    for (int i = 1; i < 16; ++i) u &= (sg[i] == sg[0]);
    uni = u;
  }

  {
    int sub = lane >> 5, l = lane & 31;
    int nl = (wave << 1) + sub;
    int node = sp[nl];
    int beg = rowptr[node], end = rowptr[node + 1];
    int deg = end - beg;
    int c = l << 3;
    float a[8];
#pragma unroll
    for (int j = 0; j < 8; ++j) a[j] = 0.f;
    acc8(a, *(const uint4*)(B + (size_t)node * 256 + c));
    int pre0 = (l < deg) ? (int)ssrc[beg + l] : 0;
    int pre1 = (32 + l < deg) ? (int)ssrc[beg + 32 + l] : 0;
    int lim = deg < 64 ? deg : 64;
    int i = 0;
    for (; i + 3 < lim; i += 4) {
      uint4 v[4];
#pragma unroll
      for (int e = 0; e < 4; ++e) {
        int ee = i + e;
        int idx = __shfl(ee < 32 ? pre0 : pre1, ee & 31, 32);
        v[e] = *(const uint4*)(B + (size_t)idx * 256 + c);
      }
#pragma unroll
      for (int e = 0; e < 4; ++e) acc8(a, v[e]);
    }
    for (; i < lim; ++i) {
      int idx = __shfl(i < 32 ? pre0 : pre1, i & 31, 32);
      acc8(a, *(const uint4*)(B + (size_t)idx * 256 + c));
    }
    for (; i < deg; ++i)
      acc8(a, *(const uint4*)(B + (size_t)ssrc[beg + i] * 256 + c));
    uint4 o;
    o.x = pk2(a[1], a[0]); o.y = pk2(a[3], a[2]);
    o.z = pk2(a[5], a[4]); o.w = pk2(a[7], a[6]);
    *(uint4*)(&Alds[nl * 264 + c]) = o;
  }
  __syncthreads();

  const int m = lane & 15, q = lane >> 4;
  {  // MFMA1: K=256, each wave covers 32 cols
    f32x4 acc[2];
    acc[0] = (f32x4){0.f, 0.f, 0.f, 0.f};
    acc[1] = (f32x4){0.f, 0.f, 0.f, 0.f};
    const unsigned short* arow = &Alds[m * 264 + (q << 3)];
    const int nb = (wave << 5) + m;
#pragma unroll
    for (int kb = 0; kb < 8; ++kb) {
      bf16x8 af = *(const bf16x8*)(arow + (kb << 5));
      const unsigned short* wp = Wp2 + (((size_t)(kb << 8) + nb) * 4 + q) * 8;
      acc[0] = __builtin_amdgcn_mfma_f32_16x16x32_bf16(af, *(const bf16x8*)(wp), acc[0], 0, 0, 0);
      acc[1] = __builtin_amdgcn_mfma_f32_16x16x32_bf16(af, *(const bf16x8*)(wp + 512), acc[1], 0, 0, 0);
    }
#pragma unroll
    for (int t = 0; t < 2; ++t) {
      int n = (wave << 5) + (t << 4) + m;
      float bv = b2f(Wb[512 + n]);
#pragma unroll
      for (int i = 0; i < 4; ++i)
        Tlds[((q << 2) + i) * 264 + n] = f2b(fmaxf(acc[t][i] + bv, 0.f));
    }
  }
  __syncthreads();

  {  // MFMA2: K=256 -> pool epilogue
    f32x4 acc[2];
    acc[0] = (f32x4){0.f, 0.f, 0.f, 0.f};
    acc[1] = (f32x4){0.f, 0.f, 0.f, 0.f};
    const unsigned short* arow = &Tlds[m * 264 + (q << 3)];
    const int nb = (wave << 5) + m;
#pragma unroll
    for (int kb = 0; kb < 8; ++kb) {
      bf16x8 af = *(const bf16x8*)(arow + (kb << 5));
      const unsigned short* wp = Wp3 + (((size_t)(kb << 8) + nb) * 4 + q) * 8;
      acc[0] = __builtin_amdgcn_mfma_f32_16x16x32_bf16(af, *(const bf16x8*)(wp), acc[0], 0, 0, 0);
      acc[1] = __builtin_amdgcn_mfma_f32_16x16x32_bf16(af, *(const bf16x8*)(wp + 512), acc[1], 0, 0, 0);
    }
    float* pr = pool32 + ((blockIdx.x & (NREP - 1)) << 14);
    int u = uni;
#pragma unroll
    for (int t = 0; t < 2; ++t) {
      int n = (wave << 5) + (t << 4) + m;
      float bv = b2f(Wb[768 + n]);
      float v0 = fmaxf(acc[t][0] + bv, 0.f);
      float v1 = fmaxf(acc[t][1] + bv, 0.f);
      float v2 = fmaxf(acc[t][2] + bv, 0.f);
      float v3 = fmaxf(acc[t][3] + bv, 0.f);
      if (u) {
        float ps = v0 + v1 + v2 + v3;
        ps += __shfl_xor(ps, 16);
        ps += __shfl_xor(ps, 32);
        if (q == 0) unsafeAtomicAdd(&pr[sg[0] * 256 + n], ps);
      } else {
        float vv[4] = {v0, v1, v2, v3};
        int gp = sg[q << 2];
        float a = 0.f;
#pragma unroll
        for (int i = 0; i < 4; ++i) {
          int g = sg[(q << 2) + i];
          if (g != gp) { unsafeAtomicAdd(&pr[gp * 256 + n], a); a = 0.f; gp = g; }
          a += vv[i];
        }
        unsafeAtomicAdd(&pr[gp * 256 + n], a);
      }
    }
  }
}

// ---- finalize: sum replicas, divide, dtype-aware store
__device__ __forceinline__ int lower_bound(const int* a, int n, int v, int is64) {
  int lo = 0, hi = n;
  while (lo < hi) {
    int mid = (lo + hi) >> 1;
    int bv = is64 ? a[2 * mid] : a[mid];
    if (bv < v) lo = mid + 1; else hi = mid;
  }
  return lo;
}

__global__ void pool_final(const float* __restrict__ pool32,
                           const int* __restrict__ batch,
                           void* __restrict__ out,
                           const int* __restrict__ flags) {
  __shared__ int sh[2];
  int g = blockIdx.x;
  int is64 = flags[1];
  if (threadIdx.x == 0) sh[0] = lower_bound(batch, N_NODES, g, is64);
  if (threadIdx.x == 1) sh[1] = lower_bound(batch, N_NODES, g + 1, is64);
  __syncthreads();
  int c = threadIdx.x;
  float s = 0.f;
#pragma unroll
  for (int r = 0; r < NREP; ++r) s += pool32[(r << 14) + g * 256 + c];
  float res = s / fmaxf((float)(sh[1] - sh[0]), 1.0f);
  if (flags[0]) ((unsigned short*)out)[(size_t)g * 256 + c] = f2b(res);
  else          ((float*)out)[(size_t)g * 256 + c] = res;
}

extern "C" void kernel_launch(void* const* d_in, const int* in_sizes, int n_in,
                              void* d_out, int out_size, void* d_ws, size_t ws_size,
                              hipStream_t stream) {
  const void* x    = d_in[0];
  const int*  ei   = (const int*)d_in[1];
  const int*  batch= (const int*)d_in[2];

  char* ws = (char*)d_ws;
  int*            flags = (int*)(ws + OFF_FLAGS);
  unsigned short* Wb    = (unsigned short*)(ws + OFF_WB);
  unsigned short* Wp0   = (unsigned short*)(ws + OFF_WP0);
  unsigned short* Wp1   = (unsigned short*)(ws + OFF_WP1);
  unsigned short* Wp2   = (unsigned short*)(ws + OFF_WP2);
  unsigned short* Wp3   = (unsigned short*)(ws + OFF_WP3);
  int*            cnts  = (int*)(ws + OFF_CNT);
  int*            rowp  = (int*)(ws + OFF_ROWPTR);
  int*            curs  = (int*)(ws + OFF_CURSOR);
  unsigned short* ssrc  = (unsigned short*)(ws + OFF_SSRC);
  unsigned short* A     = (unsigned short*)(ws + OFF_A);
  unsigned short* B     = (unsigned short*)(ws + OFF_B);
  float*          pool32= (float*)(ws + OFF_POOL32);
  int*            bsum  = (int*)(ws + OFF_BSUM);
  int*            perm  = (int*)(ws + OFF_PERM);

  detect_zero<<<197, 256, 0, stream>>>((const unsigned int*)x, (const unsigned int*)ei,
                                       flags, cnts);
  prep_kernel<<<PB_TOTAL, 256, 0, stream>>>(x, ei,
                                            d_in[3], d_in[5], d_in[7], d_in[9],
                                            d_in[4], d_in[6], d_in[8], d_in[10],
                                            A, cnts, Wp0, Wp1, Wp2, Wp3, Wb, flags);
  scan_blocks<<<SCAN_BLOCKS, 256, 0, stream>>>(cnts, rowp, bsum, pool32);
  scan_fix<<<SCAN_BLOCKS, 256, 0, stream>>>(rowp, curs, bsum, cnts, perm);
  fill_kernel<<<3125, 256, 0, stream>>>(ei, curs, ssrc, flags);

  fused_layer1<<<3125, 256, 0, stream>>>(A, (const unsigned short*)x, rowp, ssrc,
                                         perm, Wp0, Wp1, Wb, B, flags);
  fused_layer2<<<3125, 512, 0, stream>>>(B, rowp, ssrc, perm, Wp2, Wp3, Wb,
                                         pool32, batch, flags);

  pool_final<<<N_GRAPHS, 256, 0, stream>>>(pool32, batch, d_out, flags);
}